// Round 3
// baseline (1334.707 us; speedup 1.0000x reference)
//
#include <hip/hip_runtime.h>
#include <stdint.h>

#define NB 4
#define NN 8192
#define KNB 30
#define TOT (NB * NN)

// ---------------- threefry2x32 (JAX-exact, key = [0, 42]) ----------------
__device__ __forceinline__ uint32_t rotl32(uint32_t v, int r) {
    return (v << r) | (v >> (32 - r));
}

__device__ __forceinline__ void threefry(uint32_t x0, uint32_t x1,
                                         uint32_t& o0, uint32_t& o1) {
    const uint32_t ks0 = 0u, ks1 = 42u, ks2 = 0u ^ 42u ^ 0x1BD11BDAu;
    x0 += ks0; x1 += ks1;
#define RND(r) { x0 += x1; x1 = rotl32(x1, r); x1 ^= x0; }
    RND(13) RND(15) RND(26) RND(6)
    x0 += ks1; x1 += ks2 + 1u;
    RND(17) RND(29) RND(16) RND(24)
    x0 += ks2; x1 += ks0 + 2u;
    RND(13) RND(15) RND(26) RND(6)
    x0 += ks0; x1 += ks1 + 3u;
    RND(17) RND(29) RND(16) RND(24)
    x0 += ks1; x1 += ks2 + 4u;
    RND(13) RND(15) RND(26) RND(6)
    x0 += ks2; x1 += ks0 + 5u;
#undef RND
    o0 = x0; o1 = x1;
}

// jax_threefry_partitionable=True (default in modern JAX):
// bits[t] = o0 ^ o1 of threefry2x32(key, hi32(t)=0, lo32(t)=t)
__global__ void init_z_kernel(float* __restrict__ z) {
    int t = blockIdx.x * blockDim.x + threadIdx.x;
    if (t >= TOT) return;
    uint32_t o0, o1;
    threefry(0u, (uint32_t)t, o0, o1);
    uint32_t bits = o0 ^ o1;
    // jax.random.uniform: ((bits>>9)|0x3f800000).view(f32) - 1.0
    z[t] = __uint_as_float((bits >> 9) | 0x3f800000u) - 1.0f;
}

// ---------------- kNN: one block per (b,i) row, top-30 by 30x block-argmin ----
__global__ __launch_bounds__(256) void knn_kernel(const float* __restrict__ X,
                                                  const int* __restrict__ C,
                                                  int* __restrict__ edges) {
    const int row = blockIdx.x;          // 0..TOT-1
    const int b = row >> 13;             // row / 8192
    const int i = row & (NN - 1);
    const float* Xb = X + (size_t)b * NN * 3;
    const int* Cb = C + (size_t)b * NN;
    const float xi = Xb[i * 3 + 0], yi = Xb[i * 3 + 1], zi = Xb[i * 3 + 2];
    const int t = threadIdx.x;

    // d2 for j = s*256 + t, exact reference op order (no FMA contraction)
    float d[32];
#pragma unroll
    for (int s = 0; s < 32; ++s) {
        int j = s * 256 + t;
        float dx = __fsub_rn(xi, Xb[j * 3 + 0]);
        float dy = __fsub_rn(yi, Xb[j * 3 + 1]);
        float dz = __fsub_rn(zi, Xb[j * 3 + 2]);
        float d2 = __fadd_rn(__fadd_rn(__fmul_rn(dx, dx), __fmul_rn(dy, dy)),
                             __fmul_rn(dz, dz));
        d2 = __fadd_rn(d2, (Cb[j] > 0) ? 0.0f : 1e9f);  // (~mask_j)*BIG
        d2 = __fadd_rn(d2, (j == i) ? 1e9f : 0.0f);     // eye*BIG
        d[s] = d2;
    }

    __shared__ unsigned long long smin[4];
    unsigned long long prev = 0ull;  // last selected key (keys strictly increase)
    for (int kk = 0; kk < KNB; ++kk) {
        unsigned long long best = ~0ull;
#pragma unroll
        for (int s = 0; s < 32; ++s) {
            // d2 >= 0 -> float bits monotonic; low 32 bits = j (tie-break: lower j)
            unsigned long long key =
                ((unsigned long long)__float_as_uint(d[s]) << 32) |
                (unsigned)(s * 256 + t);
            if ((kk == 0 || key > prev) && key < best) best = key;
        }
        unsigned long long r = best;
#pragma unroll
        for (int off = 32; off >= 1; off >>= 1) {
            unsigned long long o = __shfl_xor(r, off, 64);
            r = (o < r) ? o : r;
        }
        if ((t & 63) == 0) smin[t >> 6] = r;
        __syncthreads();
        unsigned long long g0 = smin[0] < smin[1] ? smin[0] : smin[1];
        unsigned long long g1 = smin[2] < smin[3] ? smin[2] : smin[3];
        unsigned long long g = g0 < g1 ? g0 : g1;
        if (t == 0) edges[(size_t)row * KNB + kk] = (int)(g & 0xffffffffu);
        prev = g;
        __syncthreads();
    }
}

// ---------------- one smoothing step (all selected neighbors are valid) -------
__global__ void smooth_kernel(const float* __restrict__ zin,
                              float* __restrict__ zout,
                              const int* __restrict__ edges,
                              const int* __restrict__ C) {
    int t = blockIdx.x * blockDim.x + threadIdx.x;
    if (t >= TOT) return;
    float acc = 0.0f;
    if (C[t] > 0) {
        const int b = t >> 13;
        const int* e = edges + (size_t)t * KNB;
        const float* zb = zin + (size_t)b * NN;
#pragma unroll
        for (int k = 0; k < KNB; ++k) acc = __fadd_rn(acc, zb[e[k]]);
        acc = __fdiv_rn(acc, __fadd_rn(30.0f, 1e-5f));
    }
    // invalid rows: sum(mask*z)=0, 0/1e-5 = 0, alpha=1 -> exactly 0
    zout[t] = acc;
}

// ---------------- z += priority; stable ascending argsort per batch ----------
__global__ __launch_bounds__(1024) void sort_kernel(const float* __restrict__ z,
                                                    const float* __restrict__ prio,
                                                    int* __restrict__ out) {
    __shared__ unsigned long long keys[NN];  // 64 KiB
    const int b = blockIdx.x;
    for (int i = threadIdx.x; i < NN; i += 1024) {
        float v = z[(size_t)b * NN + i] + prio[(size_t)b * NN + i];
        uint32_t u = __float_as_uint(v);
        u ^= (u >> 31) ? 0xFFFFFFFFu : 0x80000000u;  // monotonic float->uint
        keys[i] = ((unsigned long long)u << 32) | (unsigned)i;
    }
    __syncthreads();
    for (int k = 2; k <= NN; k <<= 1) {
        for (int j = k >> 1; j > 0; j >>= 1) {
            for (int i = threadIdx.x; i < NN; i += 1024) {
                int ixj = i ^ j;
                if (ixj > i) {
                    unsigned long long a = keys[i], c = keys[ixj];
                    bool up = ((i & k) == 0);
                    if ((a > c) == up) { keys[i] = c; keys[ixj] = a; }
                }
            }
            __syncthreads();
        }
    }
    for (int i = threadIdx.x; i < NN; i += 1024)
        out[(size_t)b * NN + i] = (int)(keys[i] & 0xffffffffu);
}

extern "C" void kernel_launch(void* const* d_in, const int* in_sizes, int n_in,
                              void* d_out, int out_size, void* d_ws, size_t ws_size,
                              hipStream_t stream) {
    const float* X = (const float*)d_in[0];    // [4,8192,3] f32
    const int* C = (const int*)d_in[1];        // [4,8192] int32 (x64-disabled JAX)
    const float* prio = (const float*)d_in[2]; // [4,8192] f32
    int* out = (int*)d_out;                    // [4,8192] i32

    float* z0 = (float*)d_ws;
    float* z1 = z0 + TOT;
    int* edges = (int*)(z1 + TOT);  // TOT*30 ints (~3.9 MB)

    init_z_kernel<<<TOT / 256, 256, 0, stream>>>(z0);
    knn_kernel<<<TOT, 256, 0, stream>>>(X, C, edges);

    float* cur = z0;
    float* nxt = z1;
    for (int s = 0; s < 5; ++s) {
        smooth_kernel<<<TOT / 256, 256, 0, stream>>>(cur, nxt, edges, C);
        float* tmp = cur; cur = nxt; nxt = tmp;
    }
    sort_kernel<<<NB, 1024, 0, stream>>>(cur, prio, out);
}